// Round 12
// baseline (130.818 us; speedup 1.0000x reference)
//
#include <hip/hip_runtime.h>
#include <stdint.h>

#define N_WORDS 8192
#define LOG2E_8 0.18033688011112043f   // log2(e)/sqrt(64)

typedef __attribute__((ext_vector_type(8))) short short8;
typedef __attribute__((ext_vector_type(4))) float f32x4;
typedef __attribute__((ext_vector_type(16))) float f32x16;
typedef __attribute__((ext_vector_type(2))) __fp16 pkhalf2;   // cvt_pkrtz return type
typedef __attribute__((ext_vector_type(4))) _Float16 half4;
typedef __attribute__((ext_vector_type(8))) _Float16 half8;

__device__ __forceinline__ unsigned short f32_to_bf16(float f) {
    union { float f; unsigned u; } v; v.f = f;
    unsigned u = v.u;
    return (unsigned short)((u + 0x7FFFu + ((u >> 16) & 1u)) >> 16);
}

__device__ __forceinline__ unsigned short f32_to_f16(float f) {
    union { _Float16 h; unsigned short u; } cv;
    cv.h = (_Float16)f;
    return cv.u;
}

// global -> LDS direct copy, 16B per lane. LDS dest must be wave-uniform base;
// HW adds lane*16. Global ptr is per-lane.
__device__ __forceinline__ void async16(const void* g, void* l) {
    __builtin_amdgcn_global_load_lds(
        (const __attribute__((address_space(1))) unsigned int*)g,
        (__attribute__((address_space(3))) unsigned int*)l, 16, 0, 0);
}

// ---------------------------------------------------------------------------
// Kernel 1: QKV projection as bf16 MFMA GEMM: [8192x512] @ [512x64] x3 mats,
// plus (blockIdx.y==3) the w_o_eff fold:
//   weT[j][p] = (f16) sum_h wo[h*64+p][j]   (transposed, B-frag ready)
// grid (128, 4), 256 thr -> 512 blocks = 2/CU (validated structure).
// Outputs (fragment-major K/V, validated R10: attn LDS reads become
// lane-contiguous b128 = zero bank conflicts):
//   qB bf16 [row][64], cols XOR-swizzled in 8-elem chunks, pre-scaled by
//      log2e/8
//   kB bf16: per 128-row tile (16KB contiguous): region (nt*4+c) of 1KB,
//      lane L=hi*32+l31 holds K[row=tile*128+nt*32+l31][n=(2c+hi)*8+j] at
//      L*16B + j*2B.
//   vH f16: per 128-krow tile (16KB contiguous): region ((nt*2+m)*2+vt) of
//      1KB, lane L holds V[krow=tile*128+32nt+16m+4hi+(j&3)+8(j>>2)]
//      [vcol=32vt+l31] at L*16B + j*2B.
// ---------------------------------------------------------------------------
__global__ __launch_bounds__(256) void qkv_gemm(
    const float* __restrict__ x,
    const float* __restrict__ wq, const float* __restrict__ wk,
    const float* __restrict__ wv, const float* __restrict__ wo,
    unsigned short* __restrict__ qB, unsigned short* __restrict__ kB,
    unsigned short* __restrict__ vH, unsigned short* __restrict__ weT)
{
    int t = threadIdx.x;
    int mat = blockIdx.y;

    if (mat == 3) {
        // w_o_eff fold: coalesced reads over j; f16 transposed scatter store
        int i = blockIdx.x * 256 + t;
        int p = i >> 9;
        int j = i & 511;
        float s = 0.0f;
#pragma unroll
        for (int h = 0; h < 8; ++h) s += wo[(size_t)(h * 64 + p) * 512 + j];
        weT[(size_t)j * 64 + p] = f32_to_f16(s);
        return;
    }

    __shared__ __align__(16) unsigned short ldsX[64 * 72];  // [m][k] pitch 72
    __shared__ __align__(16) unsigned short ldsW[64 * 72];  // [n][k] pitch 72

    int mt = blockIdx.x;
    const float* w = (mat == 0) ? wq : (mat == 1) ? wk : wv;

    int wvid = t >> 6, lane = t & 63;
    int lq = lane & 15, quad = lane >> 4;

    f32x4 acc[4];
#pragma unroll
    for (int nt = 0; nt < 4; ++nt) acc[nt] = (f32x4){0.f, 0.f, 0.f, 0.f};

    // prefetch registers
    float4 xr[4];
    float wr[16];
    int wn = t & 63, wkbs = (t >> 6) * 16;

    // prologue: load tile kb=0
    {
#pragma unroll
        for (int j2 = 0; j2 < 4; ++j2) {
            int i = t + j2 * 256;
            int row = i >> 4, c4 = (i & 15) * 4;
            xr[j2] = *(const float4*)(x + (size_t)(mt * 64 + row) * 512 + c4);
        }
#pragma unroll
        for (int kk = 0; kk < 16; ++kk)
            wr[kk] = w[(size_t)(wkbs + kk) * 64 + wn];
    }

    for (int kb = 0; kb < 8; ++kb) {
        __syncthreads();   // all waves finished reading LDS of previous tile
        // store prefetched registers -> LDS (f32 -> bf16)
#pragma unroll
        for (int j2 = 0; j2 < 4; ++j2) {
            int i = t + j2 * 256;
            int row = i >> 4, c4 = (i & 15) * 4;
            unsigned p0 = f32_to_bf16(xr[j2].x) | ((unsigned)f32_to_bf16(xr[j2].y) << 16);
            unsigned p1 = f32_to_bf16(xr[j2].z) | ((unsigned)f32_to_bf16(xr[j2].w) << 16);
            *(uint2*)(&ldsX[row * 72 + c4]) = make_uint2(p0, p1);
        }
#pragma unroll
        for (int kk = 0; kk < 16; kk += 2) {
            unsigned p = f32_to_bf16(wr[kk]) | ((unsigned)f32_to_bf16(wr[kk + 1]) << 16);
            *(unsigned*)(&ldsW[wn * 72 + wkbs + kk]) = p;
        }
        __syncthreads();

        // issue next tile's global loads early; they complete under the MFMAs
        if (kb < 7) {
            int k0 = (kb + 1) * 64;
#pragma unroll
            for (int j2 = 0; j2 < 4; ++j2) {
                int i = t + j2 * 256;
                int row = i >> 4, c4 = (i & 15) * 4;
                xr[j2] = *(const float4*)(x + (size_t)(mt * 64 + row) * 512 + k0 + c4);
            }
#pragma unroll
            for (int kk = 0; kk < 16; ++kk)
                wr[kk] = w[(size_t)(k0 + wkbs + kk) * 64 + wn];
        }

        int m = wvid * 16 + lq;
        short8 a0 = *(const short8*)(&ldsX[m * 72 + quad * 8]);
        short8 a1 = *(const short8*)(&ldsX[m * 72 + 32 + quad * 8]);
#pragma unroll
        for (int nt = 0; nt < 4; ++nt) {
            short8 b0 = *(const short8*)(&ldsW[(nt * 16 + lq) * 72 + quad * 8]);
            short8 b1 = *(const short8*)(&ldsW[(nt * 16 + lq) * 72 + 32 + quad * 8]);
            acc[nt] = __builtin_amdgcn_mfma_f32_16x16x32_bf16(a0, b0, acc[nt], 0, 0, 0);
            acc[nt] = __builtin_amdgcn_mfma_f32_16x16x32_bf16(a1, b1, acc[nt], 0, 0, 0);
        }
    }

    int mrow_base = mt * 64 + wvid * 16;
#pragma unroll
    for (int nt = 0; nt < 4; ++nt) {
#pragma unroll
        for (int r = 0; r < 4; ++r) {
            int row = mrow_base + quad * 4 + r;
            int n = nt * 16 + lq;
            float v = acc[nt][r];
            if (mat == 0) {
                v *= LOG2E_8;
                int col = ((((n >> 3) ^ (row & 7)) << 3)) | (n & 7);
                qB[(size_t)row * 64 + col] = f32_to_bf16(v);
            } else if (mat == 1) {
                // fragment-major kB: region nt*4+c, lane hi*32+l31, elem j
                int c2 = n >> 3;          // = 2c+hi
                int j  = n & 7;
                size_t addr = (size_t)(row >> 7) * 8192
                            + (size_t)((((row >> 5) & 3) << 2) + (c2 >> 1)) * 512
                            + (size_t)(((c2 & 1) << 5) + (row & 31)) * 8 + j;
                kB[addr] = f32_to_bf16(v);
            } else {
                // fragment-major vH: region (nt*2+m)*2+vt, lane hi*32+l31
                int kt  = row & 127;
                int nt2 = kt >> 5;
                int k32 = kt & 31;
                int m2  = k32 >> 4;
                int k16 = k32 & 15;
                int hi2 = (k16 >> 2) & 1;
                int j2  = (k16 & 3) | ((k16 >> 3) << 2);
                size_t addr = (size_t)(row >> 7) * 8192
                            + (size_t)((((nt2 << 1) + m2) << 1) + (n >> 5)) * 512
                            + (size_t)((hi2 << 5) + (n & 31)) * 8 + j2;
                vH[addr] = f32_to_f16(v);
            }
        }
    }
}

// ---------------------------------------------------------------------------
// Kernel 2: fixed-max flash attention partials, 32x32 MFMA shapes.
// R12: 4 waves/SIMD WITHOUT extra barrier-phases (R11's failure mode).
// 512-thread blocks = 8 waves x 32 qrows = 256 qrows/block; full 128-krow
// double-buffered tile (64 KB LDS) -> 2 blocks/CU -> 16 waves/CU =
// 4 waves/SIMD. S=16, grid = 32 qb x 16 = 512 blocks; s=bid&15 keeps both
// of an XCD's splits (256 KB K/V, fragment-major) L2-resident. Effects vs
// R10: barrier-phases/block 8 -> 4, each staged tile serves 8 waves (per-CU
// staging halves), waves/SIMD 2 -> 4 to cover the ~2x dependency-stall gap.
// Per-wave arithmetic BYTE-IDENTICAL to the R10 winner.
// ---------------------------------------------------------------------------
__global__ __launch_bounds__(512, 4) void attn_kernel(
    const unsigned short* __restrict__ qB,
    const unsigned short* __restrict__ kB,
    const unsigned short* __restrict__ vH,
    unsigned short* __restrict__ pOh, float* __restrict__ pl,
    int nk, int sshift)
{
    __shared__ __align__(16) unsigned short ldsK[2][128 * 64];
    __shared__ __align__(16) unsigned short ldsV[2][64 * 128];

    int t = threadIdx.x;
    int bid = blockIdx.x;
    int s = bid & ((1 << sshift) - 1);   // split  -> fixed XCD (round-robin)
    int qb = bid >> sshift;              // q-block within split
    int wvid = t >> 6, lane = t & 63;
    int l31 = lane & 31, hi = lane >> 5;
    int mbase = qb * 256 + wvid * 32;
    int n0 = s * nk;

    // Q B-frags: qrow = mbase + l31; QK step c needs k-chunk (2c+hi)^(qrow&7)
    short8 qf[4];
    {
        int qrow = mbase + l31;
        const unsigned short* qr = qB + (size_t)qrow * 64;
        int s7 = qrow & 7;
#pragma unroll
        for (int c = 0; c < 4; ++c)
            qf[c] = *(const short8*)(qr + (((2 * c + hi) ^ s7) << 3));
    }

    f32x16 zero16;
#pragma unroll
    for (int i = 0; i < 16; ++i) zero16[i] = 0.f;
    f32x16 oacc[2];
    oacc[0] = zero16;
    oacc[1] = zero16;
    float lsum = 0.f;

    auto stage = [&](int buf, int nb) {
        // K and V tiles: each 16KB contiguous in global (fragment-major);
        // 512 threads x 2 slots each cover the 1024 16B slots per tile.
        const char* gK = (const char*)kB + (size_t)(nb >> 7) * 16384;
        const char* gV = (const char*)vH + (size_t)(nb >> 7) * 16384;
#pragma unroll
        for (int i = 0; i < 2; ++i) {
            int L0 = (wvid * 2 + i) * 64;
            async16(gK + (size_t)(L0 + lane) * 16, (char*)ldsK[buf] + (size_t)L0 * 16);
            async16(gV + (size_t)(L0 + lane) * 16, (char*)ldsV[buf] + (size_t)L0 * 16);
        }
    };

    int tiles = nk >> 7;
    stage(0, n0);
    int cur = 0;

    for (int tt = 0; tt < tiles; ++tt) {
        __syncthreads();   // vmcnt(0) drain + barrier: buf[cur] ready,
                           // everyone done reading buf[cur^1]
        if (tt + 1 < tiles) stage(cur ^ 1, n0 + (tt + 1) * 128);

        __builtin_amdgcn_s_setprio(1);
        const char* Kb = (const char*)ldsK[cur] + (size_t)lane * 16;
        const char* Vb = (const char*)ldsV[cur] + (size_t)lane * 16;

#pragma unroll
        for (int nt = 0; nt < 4; ++nt) {
            // S^T 32x32 tile: 4 lane-contiguous b128 reads, region offsets
            f32x16 st = zero16;
#pragma unroll
            for (int c = 0; c < 4; ++c) {
                short8 a = *(const short8*)(Kb + (nt * 4 + c) * 1024);
                st = __builtin_amdgcn_mfma_f32_32x32x16_bf16(a, qf[c], st, 0, 0, 0);
            }

            // p = exp2(s); lsum on VALU; pack regs IN ORDER -> two A half8s
            union { half8 v8[2]; pkhalf2 v2[8]; } pa;
#pragma unroll
            for (int p = 0; p < 8; ++p) {
                float e0 = exp2f(st[2 * p]);
                float e1 = exp2f(st[2 * p + 1]);
                lsum += e0 + e1;
                pa.v2[p] = __builtin_amdgcn_cvt_pkrtz(e0, e1);
            }

            // PV: per (m, vt) one lane-contiguous b128 V read
#pragma unroll
            for (int m = 0; m < 2; ++m) {
#pragma unroll
                for (int vt = 0; vt < 2; ++vt) {
                    half8 vb = *(const half8*)(Vb + (((nt * 2 + m) * 2) + vt) * 1024);
                    oacc[vt] = __builtin_amdgcn_mfma_f32_32x32x16_f16(
                        pa.v8[m], vb, oacc[vt], 0, 0, 0);
                }
            }
        }
        __builtin_amdgcn_s_setprio(0);
        cur ^= 1;
    }

    // each (l31) qrow's partial sum lives split across lane-halves
    lsum += __shfl_xor(lsum, 32);

    size_t obase = (size_t)s * N_WORDS;
    if (hi == 0) pl[obase + mbase + l31] = lsum;

    // ---- coalesced O epilogue: stage f16 O in LDS, store 16B/lane lines
    __syncthreads();   // all waves done reading K/V of the last tile
    unsigned short* ldsO = &ldsK[0][0];   // 256x64 f16 = 32 KB (both K bufs)
#pragma unroll
    for (int vt = 0; vt < 2; ++vt)
#pragma unroll
        for (int r = 0; r < 16; ++r) {
            int lrow = wvid * 32 + (r & 3) + 8 * (r >> 2) + 4 * hi;
            ldsO[lrow * 64 + vt * 32 + l31] = f32_to_f16(oacc[vt][r]);
        }
    __syncthreads();
    {
        const uint4* U = (const uint4*)ldsO;
        uint4* G = (uint4*)(pOh + (obase + (size_t)qb * 256) * 64);
#pragma unroll
        for (int j = 0; j < 4; ++j)
            G[t + 512 * j] = U[t + 512 * j];
    }
}

// ---------------------------------------------------------------------------
// Kernel 3: combine + output GEMM fused, GEMM on the MFMA pipe.
// Per block (16 rows): reduce the S split partials (f16 in, f32 accum) into a
// padded f16 LDS tile, then out = head @ weT via 16x16x32 f16 MFMA
// (A = head rows from LDS; B = weT streamed from L2, 64KB, shared by all
// blocks).
// ---------------------------------------------------------------------------
__global__ __launch_bounds__(256) void out_kernel(
    const unsigned short* __restrict__ pOh, const float* __restrict__ pl,
    const unsigned short* __restrict__ weT, float* __restrict__ out, int S)
{
    __shared__ __align__(16) _Float16 ldsH[16 * 72];  // [row][k] pitch 72
    int t = threadIdx.x;
    int r0 = blockIdx.x * 16;
    const _Float16* pOf = (const _Float16*)pOh;

    // combine: 16 rows x 64 dims; per wave: row fixed, d = lane (coalesced)
#pragma unroll
    for (int j = 0; j < 4; ++j) {
        int i = t + j * 256;
        int row = i >> 6, d = i & 63;
        float so = 0.f, sl = 0.f;
        for (int s = 0; s < S; ++s) {
            so += (float)pOf[((size_t)s * N_WORDS + r0 + row) * 64 + d];
            sl += pl[(size_t)s * N_WORDS + r0 + row];
        }
        ldsH[row * 72 + d] = (_Float16)(so / sl);
    }
    __syncthreads();

    int wv = t >> 6, lane = t & 63;
    int lq = lane & 15, quad = lane >> 4;

    // A-frag: head row = lq, k = quad*8+j (+32 for a1)
    half8 a0 = *(const half8*)(&ldsH[lq * 72 + quad * 8]);
    half8 a1 = *(const half8*)(&ldsH[lq * 72 + 32 + quad * 8]);
    const _Float16* wT = (const _Float16*)weT;

#pragma unroll
    for (int ntl = 0; ntl < 8; ++ntl) {
        int nt = wv * 8 + ntl;
        const _Float16* wrow = wT + (size_t)(nt * 16 + lq) * 64;
        half8 b0 = *(const half8*)(wrow + quad * 8);
        half8 b1 = *(const half8*)(wrow + 32 + quad * 8);
        f32x4 acc = (f32x4){0.f, 0.f, 0.f, 0.f};
        acc = __builtin_amdgcn_mfma_f32_16x16x32_f16(a0, b0, acc, 0, 0, 0);
        acc = __builtin_amdgcn_mfma_f32_16x16x32_f16(a1, b1, acc, 0, 0, 0);
#pragma unroll
        for (int r = 0; r < 4; ++r)
            out[(size_t)(r0 + quad * 4 + r) * 512 + nt * 16 + lq] = acc[r];
    }
}

// ---------------------------------------------------------------------------
extern "C" void kernel_launch(void* const* d_in, const int* in_sizes, int n_in,
                              void* d_out, int out_size, void* d_ws, size_t ws_size,
                              hipStream_t stream)
{
    const float* x  = (const float*)d_in[0];
    const float* wq = (const float*)d_in[1];
    const float* wk = (const float*)d_in[2];
    const float* wv = (const float*)d_in[3];
    const float* wo = (const float*)d_in[4];
    float* out = (float*)d_out;

    char* ws = (char*)d_ws;
    unsigned short* qB  = (unsigned short*)(ws);                   // 1 MB
    unsigned short* kB  = (unsigned short*)(ws + 1048576);         // 1 MB
    unsigned short* vH  = (unsigned short*)(ws + 2097152);         // 1 MB
    unsigned short* weT = (unsigned short*)(ws + 3145728);         // 64 KB
    float* pl           = (float*)(ws + 3211264);                  // S*32 KB (<=512 KB)
    unsigned short* pOh = (unsigned short*)(ws + 3735552);         // S*1 MB

    // S=16 (grid 512 = 2 blocks/CU at 512 thr / 64 KB LDS) if workspace
    // allows (~20.5 MB), else 8 (grid 256 = 1/CU).
    size_t base = 3735552;
    int S, sshift;
    if (ws_size >= base + 16u * 1048576u) { S = 16; sshift = 4; }
    else                                  { S = 8;  sshift = 3; }
    int nk = N_WORDS / S;
    int nqb = N_WORDS / 256;   // 32 q-blocks of 256 rows

    hipLaunchKernelGGL(qkv_gemm, dim3(128, 4), dim3(256), 0, stream,
                       x, wq, wk, wv, wo, qB, kB, vH, weT);
    hipLaunchKernelGGL(attn_kernel, dim3(nqb * S), dim3(512), 0, stream,
                       qB, kB, vH, pOh, pl, nk, sshift);
    hipLaunchKernelGGL(out_kernel, dim3(512), dim3(256), 0, stream,
                       pOh, pl, weT, out, S);
}

// Round 13
// 125.657 us; speedup vs baseline: 1.0411x; 1.0411x over previous
//
#include <hip/hip_runtime.h>
#include <stdint.h>

#define N_WORDS 8192
#define LOG2E_8 0.18033688011112043f   // log2(e)/sqrt(64)

typedef __attribute__((ext_vector_type(8))) short short8;
typedef __attribute__((ext_vector_type(4))) float f32x4;
typedef __attribute__((ext_vector_type(16))) float f32x16;
typedef __attribute__((ext_vector_type(2))) __fp16 pkhalf2;   // cvt_pkrtz return type
typedef __attribute__((ext_vector_type(4))) _Float16 half4;
typedef __attribute__((ext_vector_type(8))) _Float16 half8;

__device__ __forceinline__ unsigned short f32_to_bf16(float f) {
    union { float f; unsigned u; } v; v.f = f;
    unsigned u = v.u;
    return (unsigned short)((u + 0x7FFFu + ((u >> 16) & 1u)) >> 16);
}

__device__ __forceinline__ unsigned short f32_to_f16(float f) {
    union { _Float16 h; unsigned short u; } cv;
    cv.h = (_Float16)f;
    return cv.u;
}

// global -> LDS direct copy, 16B per lane. LDS dest must be wave-uniform base;
// HW adds lane*16. Global ptr is per-lane.
__device__ __forceinline__ void async16(const void* g, void* l) {
    __builtin_amdgcn_global_load_lds(
        (const __attribute__((address_space(1))) unsigned int*)g,
        (__attribute__((address_space(3))) unsigned int*)l, 16, 0, 0);
}

// ---------------------------------------------------------------------------
// Kernel 1: QKV projection as bf16 MFMA GEMM: [8192x512] @ [512x64] x3 mats,
// plus (blockIdx.y==3) the w_o_eff fold:
//   weT[j][p] = (f16) sum_h wo[h*64+p][j]   (transposed, B-frag ready)
// grid (128, 4), 256 thr -> 512 blocks = 2/CU (validated structure).
// R13: epilogue LDS-staged. A 64-row block's output in ALL THREE layouts is
// the contiguous byte-range dst + mt*8192 (verified from the layout algebra),
// so: stage the 8 KB image in LDS (local fragment offsets), barrier, copy
// 512 uint4 linearly. Removes R10's 1M-element scattered 2B global stores.
// Layouts (fragment-major K/V, validated R10 -> attn LDS reads are
// lane-contiguous b128, zero bank conflicts):
//   qB bf16 [row][64], cols XOR-swizzled in 8-elem chunks, pre-scaled by
//      log2e/8
//   kB bf16: per 128-row tile (16KB): region (nt*4+c) of 1KB, lane
//      L=hi*32+l31 holds K[row=tile*128+nt*32+l31][n=(2c+hi)*8+j] at
//      L*16B + j*2B.
//   vH f16: per 128-krow tile (16KB): region ((nt*2+m)*2+vt) of 1KB, lane L
//      holds V[krow=tile*128+32nt+16m+4hi+(j&3)+8(j>>2)][vcol=32vt+l31] at
//      L*16B + j*2B.
// ---------------------------------------------------------------------------
__global__ __launch_bounds__(256) void qkv_gemm(
    const float* __restrict__ x,
    const float* __restrict__ wq, const float* __restrict__ wk,
    const float* __restrict__ wv, const float* __restrict__ wo,
    unsigned short* __restrict__ qB, unsigned short* __restrict__ kB,
    unsigned short* __restrict__ vH, unsigned short* __restrict__ weT)
{
    int t = threadIdx.x;
    int mat = blockIdx.y;

    if (mat == 3) {
        // w_o_eff fold: coalesced reads over j; f16 transposed scatter store
        int i = blockIdx.x * 256 + t;
        int p = i >> 9;
        int j = i & 511;
        float s = 0.0f;
#pragma unroll
        for (int h = 0; h < 8; ++h) s += wo[(size_t)(h * 64 + p) * 512 + j];
        weT[(size_t)j * 64 + p] = f32_to_f16(s);
        return;
    }

    __shared__ __align__(16) unsigned short ldsX[64 * 72];  // [m][k] pitch 72
    __shared__ __align__(16) unsigned short ldsW[64 * 72];  // [n][k] pitch 72

    int mt = blockIdx.x;
    const float* w = (mat == 0) ? wq : (mat == 1) ? wk : wv;

    int wvid = t >> 6, lane = t & 63;
    int lq = lane & 15, quad = lane >> 4;

    f32x4 acc[4];
#pragma unroll
    for (int nt = 0; nt < 4; ++nt) acc[nt] = (f32x4){0.f, 0.f, 0.f, 0.f};

    // prefetch registers
    float4 xr[4];
    float wr[16];
    int wn = t & 63, wkbs = (t >> 6) * 16;

    // prologue: load tile kb=0
    {
#pragma unroll
        for (int j2 = 0; j2 < 4; ++j2) {
            int i = t + j2 * 256;
            int row = i >> 4, c4 = (i & 15) * 4;
            xr[j2] = *(const float4*)(x + (size_t)(mt * 64 + row) * 512 + c4);
        }
#pragma unroll
        for (int kk = 0; kk < 16; ++kk)
            wr[kk] = w[(size_t)(wkbs + kk) * 64 + wn];
    }

    for (int kb = 0; kb < 8; ++kb) {
        __syncthreads();   // all waves finished reading LDS of previous tile
        // store prefetched registers -> LDS (f32 -> bf16)
#pragma unroll
        for (int j2 = 0; j2 < 4; ++j2) {
            int i = t + j2 * 256;
            int row = i >> 4, c4 = (i & 15) * 4;
            unsigned p0 = f32_to_bf16(xr[j2].x) | ((unsigned)f32_to_bf16(xr[j2].y) << 16);
            unsigned p1 = f32_to_bf16(xr[j2].z) | ((unsigned)f32_to_bf16(xr[j2].w) << 16);
            *(uint2*)(&ldsX[row * 72 + c4]) = make_uint2(p0, p1);
        }
#pragma unroll
        for (int kk = 0; kk < 16; kk += 2) {
            unsigned p = f32_to_bf16(wr[kk]) | ((unsigned)f32_to_bf16(wr[kk + 1]) << 16);
            *(unsigned*)(&ldsW[wn * 72 + wkbs + kk]) = p;
        }
        __syncthreads();

        // issue next tile's global loads early; they complete under the MFMAs
        if (kb < 7) {
            int k0 = (kb + 1) * 64;
#pragma unroll
            for (int j2 = 0; j2 < 4; ++j2) {
                int i = t + j2 * 256;
                int row = i >> 4, c4 = (i & 15) * 4;
                xr[j2] = *(const float4*)(x + (size_t)(mt * 64 + row) * 512 + k0 + c4);
            }
#pragma unroll
            for (int kk = 0; kk < 16; ++kk)
                wr[kk] = w[(size_t)(k0 + wkbs + kk) * 64 + wn];
        }

        int m = wvid * 16 + lq;
        short8 a0 = *(const short8*)(&ldsX[m * 72 + quad * 8]);
        short8 a1 = *(const short8*)(&ldsX[m * 72 + 32 + quad * 8]);
#pragma unroll
        for (int nt = 0; nt < 4; ++nt) {
            short8 b0 = *(const short8*)(&ldsW[(nt * 16 + lq) * 72 + quad * 8]);
            short8 b1 = *(const short8*)(&ldsW[(nt * 16 + lq) * 72 + 32 + quad * 8]);
            acc[nt] = __builtin_amdgcn_mfma_f32_16x16x32_bf16(a0, b0, acc[nt], 0, 0, 0);
            acc[nt] = __builtin_amdgcn_mfma_f32_16x16x32_bf16(a1, b1, acc[nt], 0, 0, 0);
        }
    }

    // ---- R13 epilogue: stage the 8 KB output image in LDS, copy linearly
    __syncthreads();   // all waves done with ldsX/ldsW MFMA reads
    unsigned short* ldsO = ldsX;   // 8 KB needed; ldsX is 9 KB
#pragma unroll
    for (int nt = 0; nt < 4; ++nt) {
#pragma unroll
        for (int r = 0; r < 4; ++r) {
            int lr = wvid * 16 + quad * 4 + r;   // local row 0..63
            int n = nt * 16 + lq;
            float v = acc[nt][r];
            int off;
            unsigned short u;
            if (mat == 0) {
                v *= LOG2E_8;
                int col = (((n >> 3) ^ (lr & 7)) << 3) | (n & 7);
                off = lr * 64 + col;
                u = f32_to_bf16(v);
            } else if (mat == 1) {
                // local fragment-major kB image (global base mt*8192 B)
                int c2 = n >> 3, j = n & 7;
                off = (((lr >> 5) << 2) + (c2 >> 1)) * 512
                    + (((c2 & 1) << 5) + (lr & 31)) * 8 + j;
                u = f32_to_bf16(v);
            } else {
                // local fragment-major vH image (global base mt*8192 B)
                int j2 = (lr & 3) | (((lr >> 3) & 1) << 2);
                off = ((((lr >> 5) << 1) + ((lr >> 4) & 1)) * 2 + (n >> 5)) * 512
                    + ((((lr >> 2) & 1) << 5) + (n & 31)) * 8 + j2;
                u = f32_to_f16(v);
            }
            ldsO[off] = u;
        }
    }
    __syncthreads();
    {
        unsigned short* dst = (mat == 0) ? qB : (mat == 1) ? kB : vH;
        const uint4* U = (const uint4*)ldsO;
        uint4* G = (uint4*)((char*)dst + (size_t)mt * 8192);
        G[t] = U[t];
        G[t + 256] = U[t + 256];
    }
}

// ---------------------------------------------------------------------------
// Kernel 2: fixed-max flash attention partials, 32x32 MFMA shapes.
// R13 = R10 winner, byte-identical (R11/R12 occupancy experiments both
// regressed; 2 blocks/CU, 256 thr, 128-krow dbuf tiles, S=8 split-per-XCD).
// Fragment-major K/V: every compute ds_read is lane-contiguous b128
// (zero bank conflicts), V merged to single b128s, staging is linear 16KB.
// ---------------------------------------------------------------------------
__global__ __launch_bounds__(256) void attn_kernel(
    const unsigned short* __restrict__ qB,
    const unsigned short* __restrict__ kB,
    const unsigned short* __restrict__ vH,
    unsigned short* __restrict__ pOh, float* __restrict__ pl,
    int nk, int sshift)
{
    __shared__ __align__(16) unsigned short ldsK[2][128 * 64];
    __shared__ __align__(16) unsigned short ldsV[2][64 * 128];

    int t = threadIdx.x;
    int bid = blockIdx.x;
    int s = bid & ((1 << sshift) - 1);   // split  -> fixed XCD (round-robin)
    int qb = bid >> sshift;              // q-block within split
    int wvid = t >> 6, lane = t & 63;
    int l31 = lane & 31, hi = lane >> 5;
    int mbase = qb * 128 + wvid * 32;
    int n0 = s * nk;

    // Q B-frags: qrow = mbase + l31; QK step c needs k-chunk (2c+hi)^(qrow&7)
    short8 qf[4];
    {
        int qrow = mbase + l31;
        const unsigned short* qr = qB + (size_t)qrow * 64;
        int s7 = qrow & 7;
#pragma unroll
        for (int c = 0; c < 4; ++c)
            qf[c] = *(const short8*)(qr + (((2 * c + hi) ^ s7) << 3));
    }

    f32x16 zero16;
#pragma unroll
    for (int i = 0; i < 16; ++i) zero16[i] = 0.f;
    f32x16 oacc[2];
    oacc[0] = zero16;
    oacc[1] = zero16;
    float lsum = 0.f;

    auto stage = [&](int buf, int nb) {
        // K and V tiles: each 16KB contiguous in global (fragment-major)
        const char* gK = (const char*)kB + (size_t)(nb >> 7) * 16384;
        const char* gV = (const char*)vH + (size_t)(nb >> 7) * 16384;
#pragma unroll
        for (int i = 0; i < 4; ++i) {
            int L0 = (wvid * 4 + i) * 64;
            async16(gK + (size_t)(L0 + lane) * 16, (char*)ldsK[buf] + (size_t)L0 * 16);
            async16(gV + (size_t)(L0 + lane) * 16, (char*)ldsV[buf] + (size_t)L0 * 16);
        }
    };

    int tiles = nk >> 7;
    stage(0, n0);
    int cur = 0;

    for (int tt = 0; tt < tiles; ++tt) {
        __syncthreads();   // vmcnt(0) drain + barrier: buf[cur] ready,
                           // everyone done reading buf[cur^1]
        if (tt + 1 < tiles) stage(cur ^ 1, n0 + (tt + 1) * 128);

        __builtin_amdgcn_s_setprio(1);
        const char* Kb = (const char*)ldsK[cur] + (size_t)lane * 16;
        const char* Vb = (const char*)ldsV[cur] + (size_t)lane * 16;

#pragma unroll
        for (int nt = 0; nt < 4; ++nt) {
            // S^T 32x32 tile: 4 lane-contiguous b128 reads, region offsets
            f32x16 st = zero16;
#pragma unroll
            for (int c = 0; c < 4; ++c) {
                short8 a = *(const short8*)(Kb + (nt * 4 + c) * 1024);
                st = __builtin_amdgcn_mfma_f32_32x32x16_bf16(a, qf[c], st, 0, 0, 0);
            }

            // p = exp2(s); lsum on VALU; pack regs IN ORDER -> two A half8s
            union { half8 v8[2]; pkhalf2 v2[8]; } pa;
#pragma unroll
            for (int p = 0; p < 8; ++p) {
                float e0 = exp2f(st[2 * p]);
                float e1 = exp2f(st[2 * p + 1]);
                lsum += e0 + e1;
                pa.v2[p] = __builtin_amdgcn_cvt_pkrtz(e0, e1);
            }

            // PV: per (m, vt) one lane-contiguous b128 V read
#pragma unroll
            for (int m = 0; m < 2; ++m) {
#pragma unroll
                for (int vt = 0; vt < 2; ++vt) {
                    half8 vb = *(const half8*)(Vb + (((nt * 2 + m) * 2) + vt) * 1024);
                    oacc[vt] = __builtin_amdgcn_mfma_f32_32x32x16_f16(
                        pa.v8[m], vb, oacc[vt], 0, 0, 0);
                }
            }
        }
        __builtin_amdgcn_s_setprio(0);
        cur ^= 1;
    }

    // each (l31) qrow's partial sum lives split across lane-halves
    lsum += __shfl_xor(lsum, 32);

    size_t obase = (size_t)s * N_WORDS;
    if (hi == 0) pl[obase + mbase + l31] = lsum;

    // ---- coalesced O epilogue: stage f16 O in LDS, store 16B/lane lines
    __syncthreads();   // all waves done reading K/V of the last tile
    unsigned short* ldsO = &ldsK[0][0];   // 128x64 f16 = 16 KB
#pragma unroll
    for (int vt = 0; vt < 2; ++vt)
#pragma unroll
        for (int r = 0; r < 16; ++r) {
            int lrow = wvid * 32 + (r & 3) + 8 * (r >> 2) + 4 * hi;
            ldsO[lrow * 64 + vt * 32 + l31] = f32_to_f16(oacc[vt][r]);
        }
    __syncthreads();
    {
        const uint4* U = (const uint4*)ldsO;
        uint4* G = (uint4*)(pOh + (obase + (size_t)qb * 128) * 64);
#pragma unroll
        for (int j = 0; j < 4; ++j)
            G[t + 256 * j] = U[t + 256 * j];
    }
}

// ---------------------------------------------------------------------------
// Kernel 3: combine + output GEMM fused, GEMM on the MFMA pipe.
// Per block (16 rows): reduce the S split partials (f16 in, f32 accum) into a
// padded f16 LDS tile, then out = head @ weT via 16x16x32 f16 MFMA
// (A = head rows from LDS; B = weT streamed from L2, 64KB, shared by all
// blocks).
// ---------------------------------------------------------------------------
__global__ __launch_bounds__(256) void out_kernel(
    const unsigned short* __restrict__ pOh, const float* __restrict__ pl,
    const unsigned short* __restrict__ weT, float* __restrict__ out, int S)
{
    __shared__ __align__(16) _Float16 ldsH[16 * 72];  // [row][k] pitch 72
    int t = threadIdx.x;
    int r0 = blockIdx.x * 16;
    const _Float16* pOf = (const _Float16*)pOh;

    // combine: 16 rows x 64 dims; per wave: row fixed, d = lane (coalesced)
#pragma unroll
    for (int j = 0; j < 4; ++j) {
        int i = t + j * 256;
        int row = i >> 6, d = i & 63;
        float so = 0.f, sl = 0.f;
        for (int s = 0; s < S; ++s) {
            so += (float)pOf[((size_t)s * N_WORDS + r0 + row) * 64 + d];
            sl += pl[(size_t)s * N_WORDS + r0 + row];
        }
        ldsH[row * 72 + d] = (_Float16)(so / sl);
    }
    __syncthreads();

    int wv = t >> 6, lane = t & 63;
    int lq = lane & 15, quad = lane >> 4;

    // A-frag: head row = lq, k = quad*8+j (+32 for a1)
    half8 a0 = *(const half8*)(&ldsH[lq * 72 + quad * 8]);
    half8 a1 = *(const half8*)(&ldsH[lq * 72 + 32 + quad * 8]);
    const _Float16* wT = (const _Float16*)weT;

#pragma unroll
    for (int ntl = 0; ntl < 8; ++ntl) {
        int nt = wv * 8 + ntl;
        const _Float16* wrow = wT + (size_t)(nt * 16 + lq) * 64;
        half8 b0 = *(const half8*)(wrow + quad * 8);
        half8 b1 = *(const half8*)(wrow + 32 + quad * 8);
        f32x4 acc = (f32x4){0.f, 0.f, 0.f, 0.f};
        acc = __builtin_amdgcn_mfma_f32_16x16x32_f16(a0, b0, acc, 0, 0, 0);
        acc = __builtin_amdgcn_mfma_f32_16x16x32_f16(a1, b1, acc, 0, 0, 0);
#pragma unroll
        for (int r = 0; r < 4; ++r)
            out[(size_t)(r0 + quad * 4 + r) * 512 + nt * 16 + lq] = acc[r];
    }
}

// ---------------------------------------------------------------------------
extern "C" void kernel_launch(void* const* d_in, const int* in_sizes, int n_in,
                              void* d_out, int out_size, void* d_ws, size_t ws_size,
                              hipStream_t stream)
{
    const float* x  = (const float*)d_in[0];
    const float* wq = (const float*)d_in[1];
    const float* wk = (const float*)d_in[2];
    const float* wv = (const float*)d_in[3];
    const float* wo = (const float*)d_in[4];
    float* out = (float*)d_out;

    char* ws = (char*)d_ws;
    unsigned short* qB  = (unsigned short*)(ws);                   // 1 MB
    unsigned short* kB  = (unsigned short*)(ws + 1048576);         // 1 MB
    unsigned short* vH  = (unsigned short*)(ws + 2097152);         // 1 MB
    unsigned short* weT = (unsigned short*)(ws + 3145728);         // 64 KB
    float* pl           = (float*)(ws + 3211264);                  // S*32 KB
    unsigned short* pOh = (unsigned short*)(ws + 3735552);         // S*1 MB

    // S=8 (one split per XCD) if workspace allows, else 4.
    size_t base = 3735552;
    int S = (ws_size >= base + 8u * 1048576u) ? 8 : 4;
    int sshift = (S == 8) ? 3 : 2;
    int nk = N_WORDS / S;

    hipLaunchKernelGGL(qkv_gemm, dim3(128, 4), dim3(256), 0, stream,
                       x, wq, wk, wv, wo, qB, kB, vH, weT);
    hipLaunchKernelGGL(attn_kernel, dim3(64 * S), dim3(256), 0, stream,
                       qB, kB, vH, pOh, pl, nk, sshift);
    hipLaunchKernelGGL(out_kernel, dim3(512), dim3(256), 0, stream,
                       pOh, pl, weT, out, S);
}

// Round 14
// 124.841 us; speedup vs baseline: 1.0479x; 1.0065x over previous
//
#include <hip/hip_runtime.h>
#include <stdint.h>

#define N_WORDS 8192
#define LOG2E_8 0.18033688011112043f   // log2(e)/sqrt(64)

typedef __attribute__((ext_vector_type(8))) short short8;
typedef __attribute__((ext_vector_type(4))) float f32x4;
typedef __attribute__((ext_vector_type(16))) float f32x16;
typedef __attribute__((ext_vector_type(2))) __fp16 pkhalf2;   // cvt_pkrtz return type
typedef __attribute__((ext_vector_type(4))) _Float16 half4;
typedef __attribute__((ext_vector_type(8))) _Float16 half8;

__device__ __forceinline__ unsigned short f32_to_bf16(float f) {
    union { float f; unsigned u; } v; v.f = f;
    unsigned u = v.u;
    return (unsigned short)((u + 0x7FFFu + ((u >> 16) & 1u)) >> 16);
}

__device__ __forceinline__ unsigned short f32_to_f16(float f) {
    union { _Float16 h; unsigned short u; } cv;
    cv.h = (_Float16)f;
    return cv.u;
}

// global -> LDS direct copy, 16B per lane. LDS dest must be wave-uniform base;
// HW adds lane*16. Global ptr is per-lane.
__device__ __forceinline__ void async16(const void* g, void* l) {
    __builtin_amdgcn_global_load_lds(
        (const __attribute__((address_space(1))) unsigned int*)g,
        (__attribute__((address_space(3))) unsigned int*)l, 16, 0, 0);
}

// ---------------------------------------------------------------------------
// Kernel 1: QKV projection as bf16 MFMA GEMM: [8192x512] @ [512x64] x3 mats,
// plus (blockIdx.y==3) the w_o_eff fold:
//   weT[j][p] = (f16) sum_h wo[h*64+p][j]   (transposed, B-frag ready)
// grid (128, 4), 256 thr -> 512 blocks = 2/CU. LDS-staged epilogue (R13):
// each 64-row block's output in all three layouts is the contiguous range
// dst + mt*8192; stage in LDS, copy 512 uint4 linearly.
// Layouts (fragment-major K/V, validated R10):
//   qB bf16 [row][64], cols XOR-swizzled in 8-elem chunks, pre-scaled by
//      log2e/8
//   kB bf16: per 128-row tile (16KB): region (nt*4+c) of 1KB, lane
//      L=hi*32+l31 holds K[row=tile*128+nt*32+l31][n=(2c+hi)*8+j] at
//      L*16B + j*2B.
//   vH f16: per 128-krow tile (16KB): region ((nt*2+m)*2+vt) of 1KB, lane L
//      holds V[krow=tile*128+32nt+16m+4hi+(j&3)+8(j>>2)][vcol=32vt+l31] at
//      L*16B + j*2B.
// ---------------------------------------------------------------------------
__global__ __launch_bounds__(256) void qkv_gemm(
    const float* __restrict__ x,
    const float* __restrict__ wq, const float* __restrict__ wk,
    const float* __restrict__ wv, const float* __restrict__ wo,
    unsigned short* __restrict__ qB, unsigned short* __restrict__ kB,
    unsigned short* __restrict__ vH, unsigned short* __restrict__ weT)
{
    int t = threadIdx.x;
    int mat = blockIdx.y;

    if (mat == 3) {
        // w_o_eff fold: coalesced reads over j; f16 transposed scatter store
        int i = blockIdx.x * 256 + t;
        int p = i >> 9;
        int j = i & 511;
        float s = 0.0f;
#pragma unroll
        for (int h = 0; h < 8; ++h) s += wo[(size_t)(h * 64 + p) * 512 + j];
        weT[(size_t)j * 64 + p] = f32_to_f16(s);
        return;
    }

    __shared__ __align__(16) unsigned short ldsX[64 * 72];  // [m][k] pitch 72
    __shared__ __align__(16) unsigned short ldsW[64 * 72];  // [n][k] pitch 72

    int mt = blockIdx.x;
    const float* w = (mat == 0) ? wq : (mat == 1) ? wk : wv;

    int wvid = t >> 6, lane = t & 63;
    int lq = lane & 15, quad = lane >> 4;

    f32x4 acc[4];
#pragma unroll
    for (int nt = 0; nt < 4; ++nt) acc[nt] = (f32x4){0.f, 0.f, 0.f, 0.f};

    // prefetch registers
    float4 xr[4];
    float wr[16];
    int wn = t & 63, wkbs = (t >> 6) * 16;

    // prologue: load tile kb=0
    {
#pragma unroll
        for (int j2 = 0; j2 < 4; ++j2) {
            int i = t + j2 * 256;
            int row = i >> 4, c4 = (i & 15) * 4;
            xr[j2] = *(const float4*)(x + (size_t)(mt * 64 + row) * 512 + c4);
        }
#pragma unroll
        for (int kk = 0; kk < 16; ++kk)
            wr[kk] = w[(size_t)(wkbs + kk) * 64 + wn];
    }

    for (int kb = 0; kb < 8; ++kb) {
        __syncthreads();   // all waves finished reading LDS of previous tile
        // store prefetched registers -> LDS (f32 -> bf16)
#pragma unroll
        for (int j2 = 0; j2 < 4; ++j2) {
            int i = t + j2 * 256;
            int row = i >> 4, c4 = (i & 15) * 4;
            unsigned p0 = f32_to_bf16(xr[j2].x) | ((unsigned)f32_to_bf16(xr[j2].y) << 16);
            unsigned p1 = f32_to_bf16(xr[j2].z) | ((unsigned)f32_to_bf16(xr[j2].w) << 16);
            *(uint2*)(&ldsX[row * 72 + c4]) = make_uint2(p0, p1);
        }
#pragma unroll
        for (int kk = 0; kk < 16; kk += 2) {
            unsigned p = f32_to_bf16(wr[kk]) | ((unsigned)f32_to_bf16(wr[kk + 1]) << 16);
            *(unsigned*)(&ldsW[wn * 72 + wkbs + kk]) = p;
        }
        __syncthreads();

        // issue next tile's global loads early; they complete under the MFMAs
        if (kb < 7) {
            int k0 = (kb + 1) * 64;
#pragma unroll
            for (int j2 = 0; j2 < 4; ++j2) {
                int i = t + j2 * 256;
                int row = i >> 4, c4 = (i & 15) * 4;
                xr[j2] = *(const float4*)(x + (size_t)(mt * 64 + row) * 512 + k0 + c4);
            }
#pragma unroll
            for (int kk = 0; kk < 16; ++kk)
                wr[kk] = w[(size_t)(k0 + wkbs + kk) * 64 + wn];
        }

        int m = wvid * 16 + lq;
        short8 a0 = *(const short8*)(&ldsX[m * 72 + quad * 8]);
        short8 a1 = *(const short8*)(&ldsX[m * 72 + 32 + quad * 8]);
#pragma unroll
        for (int nt = 0; nt < 4; ++nt) {
            short8 b0 = *(const short8*)(&ldsW[(nt * 16 + lq) * 72 + quad * 8]);
            short8 b1 = *(const short8*)(&ldsW[(nt * 16 + lq) * 72 + 32 + quad * 8]);
            acc[nt] = __builtin_amdgcn_mfma_f32_16x16x32_bf16(a0, b0, acc[nt], 0, 0, 0);
            acc[nt] = __builtin_amdgcn_mfma_f32_16x16x32_bf16(a1, b1, acc[nt], 0, 0, 0);
        }
    }

    // ---- epilogue: stage the 8 KB output image in LDS, copy linearly
    __syncthreads();   // all waves done with ldsX/ldsW MFMA reads
    unsigned short* ldsO = ldsX;   // 8 KB needed; ldsX is 9 KB
#pragma unroll
    for (int nt = 0; nt < 4; ++nt) {
#pragma unroll
        for (int r = 0; r < 4; ++r) {
            int lr = wvid * 16 + quad * 4 + r;   // local row 0..63
            int n = nt * 16 + lq;
            float v = acc[nt][r];
            int off;
            unsigned short u;
            if (mat == 0) {
                v *= LOG2E_8;
                int col = (((n >> 3) ^ (lr & 7)) << 3) | (n & 7);
                off = lr * 64 + col;
                u = f32_to_bf16(v);
            } else if (mat == 1) {
                // local fragment-major kB image (global base mt*8192 B)
                int c2 = n >> 3, j = n & 7;
                off = (((lr >> 5) << 2) + (c2 >> 1)) * 512
                    + (((c2 & 1) << 5) + (lr & 31)) * 8 + j;
                u = f32_to_bf16(v);
            } else {
                // local fragment-major vH image (global base mt*8192 B)
                int j2 = (lr & 3) | (((lr >> 3) & 1) << 2);
                off = ((((lr >> 5) << 1) + ((lr >> 4) & 1)) * 2 + (n >> 5)) * 512
                    + ((((lr >> 2) & 1) << 5) + (n & 31)) * 8 + j2;
                u = f32_to_f16(v);
            }
            ldsO[off] = u;
        }
    }
    __syncthreads();
    {
        unsigned short* dst = (mat == 0) ? qB : (mat == 1) ? kB : vH;
        const uint4* U = (const uint4*)ldsO;
        uint4* G = (uint4*)((char*)dst + (size_t)mt * 8192);
        G[t] = U[t];
        G[t + 256] = U[t + 256];
    }
}

// ---------------------------------------------------------------------------
// Kernel 2: fixed-max flash attention partials, 32x32 MFMA shapes.
// R14: counted-vmcnt deep pipeline (T3+T4 port). 512 thr = 8 waves x 32
// qrows = 256 qrows/block; 4 LDS buffers (128 KiB, m201-verified size) ->
// 3-tile-deep prefetch. Per tile each wave issues exactly 4 global_load_lds;
// loop = s_waitcnt vmcnt(8) (tile-t's 4 oldest done, 8 IN FLIGHT ACROSS THE
// BARRIER) -> raw s_barrier (no drain) -> stage(t+3) -> compute. Buffer
// safety: stage(t+3) targets buf (t-1)&3 and the barrier guarantees all
// waves finished tile t-1. Tail peels vmcnt(4)/vmcnt(0). All LDS reads sit
// behind asm "memory" waits (no hoisting). Per-wave arithmetic byte-
// identical to R10. Grid 256 = 1 block/CU (2 waves/SIMD, same as R10);
// s=bid&7 keeps each XCD's 256 KB K/V split L2-resident.
// ---------------------------------------------------------------------------
__global__ __launch_bounds__(512, 2) void attn_kernel(
    const unsigned short* __restrict__ qB,
    const unsigned short* __restrict__ kB,
    const unsigned short* __restrict__ vH,
    unsigned short* __restrict__ pOh, float* __restrict__ pl,
    int nk, int sshift)
{
    // 128 KiB: K bufs [0,32K), V bufs [32K,64K) in ushort units (x2 bytes).
    __shared__ __align__(16) unsigned short ldsK[4][128 * 64];  // 64 KiB
    __shared__ __align__(16) unsigned short ldsV[4][64 * 128];  // 64 KiB

    int t = threadIdx.x;
    int bid = blockIdx.x;
    int s = bid & ((1 << sshift) - 1);   // split  -> fixed XCD (round-robin)
    int qb = bid >> sshift;              // q-block within split
    int wvid = t >> 6, lane = t & 63;
    int l31 = lane & 31, hi = lane >> 5;
    int mbase = qb * 256 + wvid * 32;
    int n0 = s * nk;

    // Q B-frags: qrow = mbase + l31; QK step c needs k-chunk (2c+hi)^(qrow&7)
    short8 qf[4];
    {
        int qrow = mbase + l31;
        const unsigned short* qr = qB + (size_t)qrow * 64;
        int s7 = qrow & 7;
#pragma unroll
        for (int c = 0; c < 4; ++c)
            qf[c] = *(const short8*)(qr + (((2 * c + hi) ^ s7) << 3));
    }

    f32x16 zero16;
#pragma unroll
    for (int i = 0; i < 16; ++i) zero16[i] = 0.f;
    f32x16 oacc[2];
    oacc[0] = zero16;
    oacc[1] = zero16;
    float lsum = 0.f;

    // stage tile 'ti' (global k-offset nb): 4 global_load_lds per wave
    // (2 K + 2 V), 8 waves cover the 2x16 KB fragment-major tile.
    auto stage = [&](int ti, int nb) {
        int buf = ti & 3;
        const char* gK = (const char*)kB + (size_t)(nb >> 7) * 16384;
        const char* gV = (const char*)vH + (size_t)(nb >> 7) * 16384;
        async16(gK + ((size_t)(wvid * 64) + lane) * 16,
                (char*)ldsK[buf] + (size_t)wvid * 1024);
        async16(gK + ((size_t)(512 + wvid * 64) + lane) * 16,
                (char*)ldsK[buf] + 8192 + (size_t)wvid * 1024);
        async16(gV + ((size_t)(wvid * 64) + lane) * 16,
                (char*)ldsV[buf] + (size_t)wvid * 1024);
        async16(gV + ((size_t)(512 + wvid * 64) + lane) * 16,
                (char*)ldsV[buf] + 8192 + (size_t)wvid * 1024);
    };

    int tiles = nk >> 7;   // >= 4 for S<=16
    stage(0, n0);
    stage(1, n0 + 128);
    stage(2, n0 + 256);

    for (int tt = 0; tt < tiles; ++tt) {
        int rem = tiles - 1 - tt;
        // per-wave outstanding loads: 4 x (#staged tiles not yet consumed).
        // Wait until tile tt's 4 are done; keep the younger ones in flight.
        if (rem >= 2)      asm volatile("s_waitcnt vmcnt(8)" ::: "memory");
        else if (rem == 1) asm volatile("s_waitcnt vmcnt(4)" ::: "memory");
        else               asm volatile("s_waitcnt vmcnt(0)" ::: "memory");
        __builtin_amdgcn_sched_barrier(0);
        __builtin_amdgcn_s_barrier();   // all waves: tile tt ready, tile tt-1 consumed
        __builtin_amdgcn_sched_barrier(0);

        if (tt + 3 < tiles) stage(tt + 3, n0 + (tt + 3) * 128);

        __builtin_amdgcn_s_setprio(1);
        const char* Kb = (const char*)ldsK[tt & 3] + (size_t)lane * 16;
        const char* Vb = (const char*)ldsV[tt & 3] + (size_t)lane * 16;

#pragma unroll
        for (int nt = 0; nt < 4; ++nt) {
            // S^T 32x32 tile: 4 lane-contiguous b128 reads, region offsets
            f32x16 st = zero16;
#pragma unroll
            for (int c = 0; c < 4; ++c) {
                short8 a = *(const short8*)(Kb + (nt * 4 + c) * 1024);
                st = __builtin_amdgcn_mfma_f32_32x32x16_bf16(a, qf[c], st, 0, 0, 0);
            }

            // p = exp2(s); lsum on VALU; pack regs IN ORDER -> two A half8s
            union { half8 v8[2]; pkhalf2 v2[8]; } pa;
#pragma unroll
            for (int p = 0; p < 8; ++p) {
                float e0 = exp2f(st[2 * p]);
                float e1 = exp2f(st[2 * p + 1]);
                lsum += e0 + e1;
                pa.v2[p] = __builtin_amdgcn_cvt_pkrtz(e0, e1);
            }

            // PV: per (m, vt) one lane-contiguous b128 V read
#pragma unroll
            for (int m = 0; m < 2; ++m) {
#pragma unroll
                for (int vt = 0; vt < 2; ++vt) {
                    half8 vb = *(const half8*)(Vb + (((nt * 2 + m) * 2) + vt) * 1024);
                    oacc[vt] = __builtin_amdgcn_mfma_f32_32x32x16_f16(
                        pa.v8[m], vb, oacc[vt], 0, 0, 0);
                }
            }
        }
        __builtin_amdgcn_s_setprio(0);
    }

    // each (l31) qrow's partial sum lives split across lane-halves
    lsum += __shfl_xor(lsum, 32);

    size_t obase = (size_t)s * N_WORDS;
    if (hi == 0) pl[obase + mbase + l31] = lsum;

    // ---- coalesced O epilogue: stage f16 O in LDS, store 16B/lane lines
    __syncthreads();   // full drain; all waves done reading K/V
    unsigned short* ldsO = &ldsK[0][0];   // 256x64 f16 = 32 KB (bufs 0-1)
#pragma unroll
    for (int vt = 0; vt < 2; ++vt)
#pragma unroll
        for (int r = 0; r < 16; ++r) {
            int lrow = wvid * 32 + (r & 3) + 8 * (r >> 2) + 4 * hi;
            ldsO[lrow * 64 + vt * 32 + l31] = f32_to_f16(oacc[vt][r]);
        }
    __syncthreads();
    {
        const uint4* U = (const uint4*)ldsO;
        uint4* G = (uint4*)(pOh + (obase + (size_t)qb * 256) * 64);
#pragma unroll
        for (int j = 0; j < 4; ++j)
            G[t + 512 * j] = U[t + 512 * j];
    }
}

// ---------------------------------------------------------------------------
// Kernel 3: combine + output GEMM fused, GEMM on the MFMA pipe.
// Per block (16 rows): reduce the S split partials (f16 in, f32 accum) into a
// padded f16 LDS tile, then out = head @ weT via 16x16x32 f16 MFMA
// (A = head rows from LDS; B = weT streamed from L2, 64KB, shared by all
// blocks).
// ---------------------------------------------------------------------------
__global__ __launch_bounds__(256) void out_kernel(
    const unsigned short* __restrict__ pOh, const float* __restrict__ pl,
    const unsigned short* __restrict__ weT, float* __restrict__ out, int S)
{
    __shared__ __align__(16) _Float16 ldsH[16 * 72];  // [row][k] pitch 72
    int t = threadIdx.x;
    int r0 = blockIdx.x * 16;
    const _Float16* pOf = (const _Float16*)pOh;

    // combine: 16 rows x 64 dims; per wave: row fixed, d = lane (coalesced)
#pragma unroll
    for (int j = 0; j < 4; ++j) {
        int i = t + j * 256;
        int row = i >> 6, d = i & 63;
        float so = 0.f, sl = 0.f;
        for (int s = 0; s < S; ++s) {
            so += (float)pOf[((size_t)s * N_WORDS + r0 + row) * 64 + d];
            sl += pl[(size_t)s * N_WORDS + r0 + row];
        }
        ldsH[row * 72 + d] = (_Float16)(so / sl);
    }
    __syncthreads();

    int wv = t >> 6, lane = t & 63;
    int lq = lane & 15, quad = lane >> 4;

    // A-frag: head row = lq, k = quad*8+j (+32 for a1)
    half8 a0 = *(const half8*)(&ldsH[lq * 72 + quad * 8]);
    half8 a1 = *(const half8*)(&ldsH[lq * 72 + 32 + quad * 8]);
    const _Float16* wT = (const _Float16*)weT;

#pragma unroll
    for (int ntl = 0; ntl < 8; ++ntl) {
        int nt = wv * 8 + ntl;
        const _Float16* wrow = wT + (size_t)(nt * 16 + lq) * 64;
        half8 b0 = *(const half8*)(wrow + quad * 8);
        half8 b1 = *(const half8*)(wrow + 32 + quad * 8);
        f32x4 acc = (f32x4){0.f, 0.f, 0.f, 0.f};
        acc = __builtin_amdgcn_mfma_f32_16x16x32_f16(a0, b0, acc, 0, 0, 0);
        acc = __builtin_amdgcn_mfma_f32_16x16x32_f16(a1, b1, acc, 0, 0, 0);
#pragma unroll
        for (int r = 0; r < 4; ++r)
            out[(size_t)(r0 + quad * 4 + r) * 512 + nt * 16 + lq] = acc[r];
    }
}

// ---------------------------------------------------------------------------
extern "C" void kernel_launch(void* const* d_in, const int* in_sizes, int n_in,
                              void* d_out, int out_size, void* d_ws, size_t ws_size,
                              hipStream_t stream)
{
    const float* x  = (const float*)d_in[0];
    const float* wq = (const float*)d_in[1];
    const float* wk = (const float*)d_in[2];
    const float* wv = (const float*)d_in[3];
    const float* wo = (const float*)d_in[4];
    float* out = (float*)d_out;

    char* ws = (char*)d_ws;
    unsigned short* qB  = (unsigned short*)(ws);                   // 1 MB
    unsigned short* kB  = (unsigned short*)(ws + 1048576);         // 1 MB
    unsigned short* vH  = (unsigned short*)(ws + 2097152);         // 1 MB
    unsigned short* weT = (unsigned short*)(ws + 3145728);         // 64 KB
    float* pl           = (float*)(ws + 3211264);                  // S*32 KB
    unsigned short* pOh = (unsigned short*)(ws + 3735552);         // S*1 MB

    // S=8 (one split per XCD; grid 256 = 1 block/CU at 512 thr / 128 KiB
    // LDS) if workspace allows, else 4.
    size_t base = 3735552;
    int S = (ws_size >= base + 8u * 1048576u) ? 8 : 4;
    int sshift = (S == 8) ? 3 : 2;
    int nk = N_WORDS / S;
    int nqb = N_WORDS / 256;   // 32 q-blocks of 256 rows

    hipLaunchKernelGGL(qkv_gemm, dim3(128, 4), dim3(256), 0, stream,
                       x, wq, wk, wv, wo, qB, kB, vH, weT);
    hipLaunchKernelGGL(attn_kernel, dim3(nqb * S), dim3(512), 0, stream,
                       qB, kB, vH, pOh, pl, nk, sshift);
    hipLaunchKernelGGL(out_kernel, dim3(512), dim3(256), 0, stream,
                       pOh, pl, weT, out, S);
}